// Round 16
// baseline (75.402 us; speedup 1.0000x reference)
//
#include <hip/hip_runtime.h>
#include <math.h>

#define B_ 16
#define T_ 2048
#define N_ 8
#define D_ 512
#define DTW 4           // d-tiles (of 16) per wave
#define LPAD 520        // LDS row pitch (words)
#define OUT_ELEMS (B_ * T_ * D_)   // 64 MiB of f32

// DIAGNOSTIC ROUND: prep x8 (identical work, same-address same-value
// stores), main x3 (replicas 1-2 -> disjoint ws regions; R7's WRITE_SIZE
// proved ws >= 193 MB). Main body byte-identical to R15 (best: 28.9 us)
// so total = prep@8x + main@3x splits cleanly.

// -2*pi/2048
#define NEG_W0 (-3.0679615757712823e-3f)
// -2*pi/32
#define NEG_W32 (-0.19634954084936207f)
// -2*pi/1024
#define NEG_W1024 (-6.1359231515425647e-3f)
// -2*ln(10000)/512
#define NEG_LDIV (-0.035977892078031555f)

typedef __attribute__((ext_vector_type(8))) short bf16x8;
typedef __attribute__((ext_vector_type(4))) float f32x4;

static __device__ __forceinline__ short f2bf(float f) {
  unsigned int u = __float_as_uint(f);
  unsigned int r = u + 0x7FFFu + ((u >> 16) & 1u);
  return (short)(r >> 16);
}

__global__ __launch_bounds__(1024) void prep_kernel(
    const float* __restrict__ x, const int* __restrict__ xmark,
    const float* __restrict__ convw, float* __restrict__ pmax,
    float* __restrict__ nyqS, float* __restrict__ tab,
    short* __restrict__ amat, short* __restrict__ xbf,
    short* __restrict__ cnt) {
  int tid = threadIdx.x;
  int inner = blockIdx.x % 417;           // 8 replicas do identical work

  if (inner >= 256) {
    int j = inner - 256;
    if (j < 32) {                         // ---- xbf + cnt rows ----
      int r = j * 1024 + tid;
      const float4* xr = (const float4*)(x + (size_t)r * 8);
      float4 lo = xr[0], hi = xr[1];
      bf16x8 v;
      v[0] = f2bf(lo.x); v[1] = f2bf(lo.y); v[2] = f2bf(lo.z); v[3] = f2bf(lo.w);
      v[4] = f2bf(hi.x); v[5] = f2bf(hi.y); v[6] = f2bf(hi.z); v[7] = f2bf(hi.w);
      *(bf16x8*)(xbf + (size_t)r * 8) = v;
      int4 mk = *(const int4*)(xmark + (size_t)r * 4);
      bf16x8 cv;
#pragma unroll
      for (int p = 0; p < 8; ++p) {
        int cc = (mk.x == p) + (mk.y == p) + (mk.z == p) + (mk.w == p);
        cv[p] = f2bf((float)cc);
      }
      *(bf16x8*)(cnt + (size_t)r * 8) = cv;
    } else if (j == 32) {                 // ---- amat builder ----
      if (tid < 512) {
        int d = tid;
        short row[32];
#pragma unroll
        for (int kk = 0; kk < 24; ++kk) {
          int g = kk >> 3, n = kk & 7;
          row[kk] = f2bf(convw[d * 24 + n * 3 + g]);
        }
        float divv = expf((float)(d >> 1) * NEG_LDIV);
        float s1, c1;
        sincosf(divv, &s1, &c1);
        int odd = d & 1;
        row[24] = f2bf(odd ? 1.f : 0.f);
        float ps = s1, pc = c1;
        row[25] = f2bf(odd ? pc : ps);
#pragma unroll
        for (int p = 2; p < 7; ++p) {
          float ns = fmaf(ps, c1, pc * s1);
          float nc = fmaf(pc, c1, -ps * s1);
          ps = ns; pc = nc;
          row[24 + p] = f2bf(odd ? pc : ps);
        }
        row[31] = 0;
#pragma unroll
        for (int q = 0; q < 4; ++q)
          *(bf16x8*)(amat + d * 32 + q * 8) = *(bf16x8*)&row[q * 8];
      }
    } else {                              // ---- FET tabgen (2 f4/thread) ----
      int base = (j - 33) * 2048 + tid * 2;
#pragma unroll
      for (int u = 0; u < 2; ++u) {
        int idx = base + u;
        int t = idx >> 7;
        int d4 = idx & 127;
        float ft = (float)t;
        float dv0 = expf((float)(d4 * 2) * NEG_LDIV);
        float dv1 = expf((float)(d4 * 2 + 1) * NEG_LDIV);
        f32x4 v;
        float s0, c0, s1, c1;
        sincosf(ft * dv0, &s0, &c0);
        sincosf(ft * dv1, &s1, &c1);
        v[0] = s0; v[1] = c0; v[2] = s1; v[3] = c1;
        *(f32x4*)(tab + (size_t)idx * 4) = v;
      }
    }
    return;
  }

  // ---- folded radix-32 FFT (validated R4..R15) ----
  __shared__ __align__(16) float2 ybuf[1024];
  __shared__ __align__(16) float2 Bl[1024];
  __shared__ __align__(16) float2 part[1024];
  __shared__ float swav[16];
  __shared__ float pwav[8];
  int bn = inner >> 1, parity = inner & 1;
  int b = bn >> 3, n = bn & 7;
  const float* xb = x + (size_t)b * (T_ * N_) + n;

  float va = xb[tid * 8];
  float vb = xb[(tid + 1024) * 8];
  float ea = va + vb;
  float sgn = (tid & 1) ? -ea : ea;
#pragma unroll
  for (int off = 32; off > 0; off >>= 1) sgn += __shfl_down(sgn, off);
  if ((tid & 63) == 0) swav[tid >> 6] = sgn;

  if (parity == 0) {
    ((float*)ybuf)[tid] = ea;
  } else {
    float o = va - vb;
    float c0, s0;
    sincosf((float)tid * NEG_W0, &s0, &c0);
    ybuf[tid] = make_float2(o * c0, o * s0);
  }
  __syncthreads();

  int m0 = tid & 31, t0 = tid >> 5;
  float d1 = (float)m0 * NEG_W32;
  float K1 = 2.0f * cosf(d1);
  float c = 1.f, s = 0.f, cp, sp;
  sincosf(-d1, &sp, &cp);
  float ar = 0.f, ai = 0.f;
  if (parity == 0) {
    const float* ya = (const float*)ybuf;
#pragma unroll 8
    for (int t1 = 0; t1 < 32; ++t1) {
      float y = ya[t1 * 32 + t0];
      ar = fmaf(y, c, ar); ai = fmaf(y, s, ai);
      float nc = fmaf(K1, c, -cp), ns = fmaf(K1, s, -sp);
      cp = c; sp = s; c = nc; s = ns;
    }
  } else {
#pragma unroll 8
    for (int t1 = 0; t1 < 32; ++t1) {
      float2 y = ybuf[t1 * 32 + t0];
      ar = fmaf(y.x, c, fmaf(-y.y, s, ar));
      ai = fmaf(y.x, s, fmaf(y.y, c, ai));
      float nc = fmaf(K1, c, -cp), ns = fmaf(K1, s, -sp);
      cp = c; sp = s; c = nc; s = ns;
    }
  }
  {
    float ct, st;
    sincosf((float)(t0 * m0) * NEG_W1024, &st, &ct);
    Bl[t0 * 32 + m0] = make_float2(ar * ct - ai * st, fmaf(ar, st, ai * ct));
  }
  __syncthreads();

  int m02 = tid & 31;
  int m1 = (tid >> 5) & 15;
  int h = tid >> 9;
  float d2 = (float)m1 * NEG_W32;
  float K2 = 2.0f * cosf(d2);
  int t0s = h * 16;
  float c2, s2, c2p, s2p;
  sincosf((float)t0s * d2, &s2, &c2);
  sincosf((float)(t0s - 1) * d2, &s2p, &c2p);
  float yr = 0.f, yi = 0.f;
#pragma unroll 8
  for (int jj = 0; jj < 16; ++jj) {
    float2 bv = Bl[(t0s + jj) * 32 + m02];
    yr = fmaf(bv.x, c2, fmaf(-bv.y, s2, yr));
    yi = fmaf(bv.x, s2, fmaf(bv.y, c2, yi));
    float nc = fmaf(K2, c2, -c2p), ns = fmaf(K2, s2, -s2p);
    c2p = c2; s2p = s2; c2 = nc; s2 = ns;
  }
  part[tid] = make_float2(yr, yi);
  __syncthreads();
  if (tid < 512) {
    float2 pa = part[tid], pb = part[tid + 512];
    float rr = pa.x + pb.x, ii = pa.y + pb.y;
    float P = fmaf(rr, rr, ii * ii);
#pragma unroll
    for (int off = 32; off > 0; off >>= 1) P = fmaxf(P, __shfl_down(P, off));
    if ((tid & 63) == 0) pwav[tid >> 6] = P;
  }
  __syncthreads();
  if (tid < 64) {
    float mxv = (tid < 8) ? pwav[tid] : 0.f;
    float svv = (tid < 16) ? swav[tid] : 0.f;
#pragma unroll
    for (int off = 8; off > 0; off >>= 1) {
      mxv = fmaxf(mxv, __shfl_down(mxv, off));
      svv += __shfl_down(svv, off);
    }
    if (tid == 0) {
      pmax[inner] = mxv;                  // identical value from all replicas
      if (parity == 0) nyqS[bn] = svv;
    }
  }
}

// ---- main: byte-identical compute to R15; replica 0 -> out, replicas
// 1-2 -> disjoint ws regions (honest store-BW measurement).
__global__ __launch_bounds__(512, 6) void main_kernel(
    const short* __restrict__ amat, const short* __restrict__ xbf,
    const short* __restrict__ cnt, const float* __restrict__ tab,
    const float* __restrict__ pmax, const float* __restrict__ nyqS,
    float* __restrict__ out, float* __restrict__ alt, int use_alt) {
  __shared__ __align__(16) float lds[16 * LPAD];
  int tid = threadIdx.x;
  int lane = tid & 63;
  int w = tid >> 6;
  int c = lane & 15;
  int g = lane >> 4;
  int blk = blockIdx.x;
  int rep = blk >> 10;
  int inner = blk & 1023;
  int ttile = inner & 127;
  int bg = inner >> 7;
  int t0 = ttile * 16;
  float* obase0 = (rep > 0 && use_alt) ? (alt + (size_t)(rep - 1) * OUT_ELEMS)
                                       : out;

  float w1v[2], w0v[2];
#pragma unroll
  for (int j = 0; j < 2; ++j) {
    int b = bg * 2 + j;
    int m = 0;
#pragma unroll
    for (int nn = 0; nn < 8; ++nn) {
      int bn = b * 8 + nn;
      float mx = fmaxf(pmax[2 * bn], pmax[2 * bn + 1]);
      float S = nyqS[bn];
      if (S * S > mx) ++m;
    }
    w1v[j] = (float)(8 - m) * 0.125f;
    w0v[j] = (float)m * 0.125f;
  }

  bf16x8 afrag[DTW];
  f32x4 fet[DTW];
#pragma unroll
  for (int q = 0; q < DTW; ++q) {
    int d0 = (w * DTW + q) * 16;
    afrag[q] = *(const bf16x8*)(amat + (size_t)(d0 + c) * 32 + g * 8);
    fet[q] = *(const f32x4*)(tab + (size_t)(t0 + c) * D_ + d0 + g * 4);
  }

  const f32x4 zac = {0.f, 0.f, 0.f, 0.f};
#pragma unroll
  for (int j = 0; j < 2; ++j) {
    int b = bg * 2 + j;
    bf16x8 bfrag;
    if (g < 3) {
      int row = (t0 + c + g - 1) & (T_ - 1);
      bfrag = *(const bf16x8*)(xbf + ((size_t)b * T_ + row) * 8);
    } else {
      bfrag = *(const bf16x8*)(cnt + ((size_t)b * T_ + t0 + c) * 8);
    }
    float w1 = w1v[j], w0 = w0v[j];
#pragma unroll
    for (int q = 0; q < DTW; ++q) {
      f32x4 acc = __builtin_amdgcn_mfma_f32_16x16x32_bf16(
          afrag[q], bfrag, zac, 0, 0, 0);
      f32x4 ov;
      ov[0] = fmaf(w1, fet[q][0], acc[0]);
      ov[1] = fmaf(w1, fet[q][1], acc[1]) + w0;
      ov[2] = fmaf(w1, fet[q][2], acc[2]);
      ov[3] = fmaf(w1, fet[q][3], acc[3]) + w0;
      int d0 = (w * DTW + q) * 16;
      *(f32x4*)(lds + c * LPAD + d0 + g * 4) = ov;
    }
    __syncthreads();
    float* obase = obase0 + ((size_t)b * T_ + t0) * D_;
#pragma unroll
    for (int r = 0; r < 4; ++r) {
      int e = r * 2048 + tid * 4;
      int trow = e >> 9, col = e & 511;
      f32x4 v = *(const f32x4*)(lds + trow * LPAD + col);
      *(f32x4*)(obase + e) = v;
    }
    if (j == 0) __syncthreads();
  }
}

extern "C" void kernel_launch(void* const* d_in, const int* in_sizes, int n_in,
                              void* d_out, int out_size, void* d_ws, size_t ws_size,
                              hipStream_t stream) {
  const float* x = (const float*)d_in[0];
  const int* xmark = (const int*)d_in[1];
  const float* convw = (const float*)d_in[2];
  float* out = (float*)d_out;

  char* ws = (char*)d_ws;
  float* pmax = (float*)ws;                            // 256 f
  float* nyqS = pmax + 256;                            // 128 f
  float* tab = (float*)(ws + 4096);                    // 4 MB FET
  short* amat = (short*)(ws + 4096 + 4194304);         // 32 KB
  short* xbf = (short*)(ws + 4096 + 4194304 + 32768);  // 512 KB
  short* cnt = (short*)(ws + 4096 + 4194304 + 32768 + 524288);  // 512 KB
  float* alt = (float*)(ws + (8u << 20));              // 2 x 64 MB regions
  size_t need = (8u << 20) + 2ull * (size_t)OUT_ELEMS * 4ull;
  int use_alt = (ws_size >= need) ? 1 : 0;

  // DIAGNOSTIC: prep x8, main x3
  prep_kernel<<<417 * 8, 1024, 0, stream>>>(x, xmark, convw, pmax, nyqS, tab,
                                            amat, xbf, cnt);
  main_kernel<<<1024 * 3, 512, 0, stream>>>(amat, xbf, cnt, tab, pmax, nyqS,
                                            out, alt, use_alt);
}

// Round 17
// 39.886 us; speedup vs baseline: 1.8905x; 1.8905x over previous
//
#include <hip/hip_runtime.h>
#include <math.h>

#define B_ 16
#define T_ 2048
#define N_ 8
#define D_ 512
#define DTW 4           // d-tiles (of 16) per wave
#define LPAD 520        // LDS row pitch (words)

// -2*pi/2048
#define NEG_W0 (-3.0679615757712823e-3f)
// -2*pi/32
#define NEG_W32 (-0.19634954084936207f)
// -2*pi/1024
#define NEG_W1024 (-6.1359231515425647e-3f)
// -2*ln(10000)/512
#define NEG_LDIV (-0.035977892078031555f)

typedef __attribute__((ext_vector_type(8))) short bf16x8;
typedef __attribute__((ext_vector_type(4))) float f32x4;

// fp32 -> bf16 (round-to-nearest-even)
static __device__ __forceinline__ short f2bf(float f) {
  unsigned int u = __float_as_uint(f);
  unsigned int r = u + 0x7FFFu + ((u >> 16) & 1u);
  return (short)(r >> 16);
}

// ws layout (byte offsets): [0,4096) pmax[512]+nyqS[128];
// [4K,4K+4M) FET tab f32[2048][512]; amat bf16[512][32] (32 KB);
// xbf bf16[16][2048][8] (512 KB); cnt bf16[16][2048][8] (512 KB).
// All rewritten unconditionally every call.

// ---- L1 prep_tail: 161 blocks x 1024 thr (~2 us). NO fft here.
//  blk 0..127 : FET tabgen (2 float4/thread)
//  blk 128    : amat (conv slots 0..23, temporal rows 24..30, 31=0)
//  blk 129..160: xbf (x->bf16 rows) + cnt (mark-count rows)
__global__ __launch_bounds__(1024) void prep_tail_kernel(
    const float* __restrict__ x, const int* __restrict__ xmark,
    const float* __restrict__ convw, float* __restrict__ tab,
    short* __restrict__ amat, short* __restrict__ xbf,
    short* __restrict__ cnt) {
  int tid = threadIdx.x;
  int j = blockIdx.x;
  if (j < 128) {                          // ---- FET tabgen ----
    int base = j * 2048 + tid * 2;
#pragma unroll
    for (int u = 0; u < 2; ++u) {
      int idx = base + u;
      int t = idx >> 7;
      int d4 = idx & 127;
      float ft = (float)t;
      float dv0 = expf((float)(d4 * 2) * NEG_LDIV);
      float dv1 = expf((float)(d4 * 2 + 1) * NEG_LDIV);
      f32x4 v;
      float s0, c0, s1, c1;
      sincosf(ft * dv0, &s0, &c0);
      sincosf(ft * dv1, &s1, &c1);
      v[0] = s0; v[1] = c0; v[2] = s1; v[3] = c1;
      *(f32x4*)(tab + (size_t)idx * 4) = v;
    }
  } else if (j == 128) {                  // ---- amat ----
    if (tid < 512) {
      int d = tid;
      short row[32];
#pragma unroll
      for (int kk = 0; kk < 24; ++kk) {
        int g = kk >> 3, n = kk & 7;      // A[d][g*8+n] = W[d][n][k=g]
        row[kk] = f2bf(convw[d * 24 + n * 3 + g]);
      }
      float divv = expf((float)(d >> 1) * NEG_LDIV);
      float s1, c1;
      sincosf(divv, &s1, &c1);
      int odd = d & 1;
      row[24] = f2bf(odd ? 1.f : 0.f);
      float ps = s1, pc = c1;
      row[25] = f2bf(odd ? pc : ps);
#pragma unroll
      for (int p = 2; p < 7; ++p) {
        float ns = fmaf(ps, c1, pc * s1);
        float nc = fmaf(pc, c1, -ps * s1);
        ps = ns; pc = nc;
        row[24 + p] = f2bf(odd ? pc : ps);
      }
      row[31] = 0;                        // marks < 7
#pragma unroll
      for (int q = 0; q < 4; ++q)
        *(bf16x8*)(amat + d * 32 + q * 8) = *(bf16x8*)&row[q * 8];
    }
  } else {                                // ---- xbf + cnt rows ----
    int r = (j - 129) * 1024 + tid;       // r = b*T + t, 0..32767
    const float4* xr = (const float4*)(x + (size_t)r * 8);
    float4 lo = xr[0], hi = xr[1];
    bf16x8 v;
    v[0] = f2bf(lo.x); v[1] = f2bf(lo.y); v[2] = f2bf(lo.z); v[3] = f2bf(lo.w);
    v[4] = f2bf(hi.x); v[5] = f2bf(hi.y); v[6] = f2bf(hi.z); v[7] = f2bf(hi.w);
    *(bf16x8*)(xbf + (size_t)r * 8) = v;
    int4 mk = *(const int4*)(xmark + (size_t)r * 4);
    bf16x8 cv;
#pragma unroll
    for (int p = 0; p < 8; ++p) {
      int cc = (mk.x == p) + (mk.y == p) + (mk.z == p) + (mk.w == p);
      cv[p] = f2bf((float)cc);
    }
    *(bf16x8*)(cnt + (size_t)r * 8) = cv;
  }
}

// ---- L2 fused: 1536 blocks x 512 thr.
//  blk 0..511  : fft (R14's validated 512-thr form): block = (bn,parity,h);
//                radix-32 two-stage folded DFT; stage 1 duplicated across
//                h-siblings; pmax[blk] = partial max (4/bn); nyqS[bn].
//  blk 512..1535: main (R15's validated form) with w1=1, w0=0 — NO fft
//                dependency; reads tab/amat/xbf/cnt, writes out.
//  Disjoint data between the two halves -> no intra-launch ordering needed.
__global__ __launch_bounds__(512, 6) void fused_kernel(
    const float* __restrict__ x, const short* __restrict__ amat,
    const short* __restrict__ xbf, const short* __restrict__ cnt,
    const float* __restrict__ tab, float* __restrict__ pmax,
    float* __restrict__ nyqS, float* __restrict__ out) {
  __shared__ __align__(16) float smem[16 * LPAD];   // 33 KB, shared by both roles
  int tid = threadIdx.x;
  int blk = blockIdx.x;

  if (blk < 512) {
    // ---- fft role ---- (aliases into smem: 2048+2048+1024+8+4 floats < 8320)
    float2* ybuf = (float2*)smem;          // [1024]
    float2* Bl = (float2*)(smem + 2048);   // [1024]
    float2* part = (float2*)(smem + 4096); // [512]
    float* swav = smem + 5120;             // [8]
    float* pwav = smem + 5128;             // [4]
    int bn = blk >> 2;
    int parity = (blk >> 1) & 1;
    int h = blk & 1;
    int b = bn >> 3, n = bn & 7;
    const float* xb = x + (size_t)b * (T_ * N_) + n;

    float v0 = xb[tid * 8];
    float v1 = xb[(tid + 512) * 8];
    float v2 = xb[(tid + 1024) * 8];
    float v3 = xb[(tid + 1536) * 8];
    float ea = v0 + v2, eb = v1 + v3;      // e[tid], e[tid+512]
    float sgn = (tid & 1) ? -(ea + eb) : (ea + eb);  // (-1)^t e_t partial
#pragma unroll
    for (int off = 32; off > 0; off >>= 1) sgn += __shfl_down(sgn, off);
    if ((tid & 63) == 0) swav[tid >> 6] = sgn;

    if (parity == 0) {
      float* ya = (float*)ybuf;
      ya[tid] = ea;
      ya[tid + 512] = eb;
    } else {
      float oa = v0 - v2, ob = v1 - v3;
      float ca, sa, cb, sb;
      sincosf((float)tid * NEG_W0, &sa, &ca);
      sincosf((float)(tid + 512) * NEG_W0, &sb, &cb);
      ybuf[tid] = make_float2(oa * ca, oa * sa);
      ybuf[tid + 512] = make_float2(ob * cb, ob * sb);
    }
    __syncthreads();

    // stage 1: thread (t0a=tid>>5 in [0,16), m0=tid&31), two t0 per chain
    int m0 = tid & 31, t0a = tid >> 5;
    float d1 = (float)m0 * NEG_W32;
    float K1 = 2.0f * cosf(d1);
    float c = 1.f, s = 0.f, cp, sp;
    sincosf(-d1, &sp, &cp);
    float ar0 = 0.f, ai0 = 0.f, ar1 = 0.f, ai1 = 0.f;
    if (parity == 0) {
      const float* ya = (const float*)ybuf;
#pragma unroll 8
      for (int t1 = 0; t1 < 32; ++t1) {
        float y0 = ya[t1 * 32 + t0a];
        float y1 = ya[t1 * 32 + t0a + 16];
        ar0 = fmaf(y0, c, ar0); ai0 = fmaf(y0, s, ai0);
        ar1 = fmaf(y1, c, ar1); ai1 = fmaf(y1, s, ai1);
        float nc = fmaf(K1, c, -cp), ns = fmaf(K1, s, -sp);
        cp = c; sp = s; c = nc; s = ns;
      }
    } else {
#pragma unroll 8
      for (int t1 = 0; t1 < 32; ++t1) {
        float2 y0 = ybuf[t1 * 32 + t0a];
        float2 y1 = ybuf[t1 * 32 + t0a + 16];
        ar0 = fmaf(y0.x, c, fmaf(-y0.y, s, ar0));
        ai0 = fmaf(y0.x, s, fmaf(y0.y, c, ai0));
        ar1 = fmaf(y1.x, c, fmaf(-y1.y, s, ar1));
        ai1 = fmaf(y1.x, s, fmaf(y1.y, c, ai1));
        float nc = fmaf(K1, c, -cp), ns = fmaf(K1, s, -sp);
        cp = c; sp = s; c = nc; s = ns;
      }
    }
    {
      float ct, st;
      sincosf((float)(t0a * m0) * NEG_W1024, &st, &ct);
      Bl[t0a * 32 + m0] =
          make_float2(ar0 * ct - ai0 * st, fmaf(ar0, st, ai0 * ct));
      sincosf((float)((t0a + 16) * m0) * NEG_W1024, &st, &ct);
      Bl[(t0a + 16) * 32 + m0] =
          make_float2(ar1 * ct - ai1 * st, fmaf(ar1, st, ai1 * ct));
    }
    __syncthreads();

    // stage 2: this block's m1 in [h*8, h*8+8); 2 threads/bin over t0-halves
    int m02 = tid & 31;
    int m1 = h * 8 + ((tid >> 5) & 7);
    int th = tid >> 8;
    float d2 = (float)m1 * NEG_W32;
    float K2 = 2.0f * cosf(d2);
    int t0s = th * 16;
    float c2, s2, c2p, s2p;
    sincosf((float)t0s * d2, &s2, &c2);
    sincosf((float)(t0s - 1) * d2, &s2p, &c2p);
    float yr = 0.f, yi = 0.f;
#pragma unroll 8
    for (int jj = 0; jj < 16; ++jj) {
      float2 bv = Bl[(t0s + jj) * 32 + m02];
      yr = fmaf(bv.x, c2, fmaf(-bv.y, s2, yr));
      yi = fmaf(bv.x, s2, fmaf(bv.y, c2, yi));
      float nc = fmaf(K2, c2, -c2p), ns = fmaf(K2, s2, -s2p);
      c2p = c2; s2p = s2; c2 = nc; s2 = ns;
    }
    part[tid] = make_float2(yr, yi);
    __syncthreads();
    if (tid < 256) {
      float2 pa = part[tid], pb = part[tid + 256];
      float rr = pa.x + pb.x, ii = pa.y + pb.y;
      float P = fmaf(rr, rr, ii * ii);
#pragma unroll
      for (int off = 32; off > 0; off >>= 1) P = fmaxf(P, __shfl_down(P, off));
      if ((tid & 63) == 0) pwav[tid >> 6] = P;
    }
    __syncthreads();
    if (tid < 64) {
      float mxv = (tid < 4) ? pwav[tid] : 0.f;
      float svv = (tid < 8) ? swav[tid] : 0.f;
#pragma unroll
      for (int off = 4; off > 0; off >>= 1) {
        mxv = fmaxf(mxv, __shfl_down(mxv, off));
        svv += __shfl_down(svv, off);
      }
      if (tid == 0) {
        pmax[blk] = mxv;                  // unconditional plain store
        if (parity == 0) nyqS[bn] = svv;  // h-siblings store same value
      }
    }
    return;
  }

  // ---- main role (R15 body, w1=1 / w0=0) ----
  float* lds = smem;
  int lane = tid & 63;
  int w = tid >> 6;
  int c = lane & 15;
  int g = lane >> 4;
  int inner = blk - 512;
  int ttile = inner & 127;
  int bg = inner >> 7;
  int t0 = ttile * 16;

  bf16x8 afrag[DTW];
  f32x4 fet[DTW];
#pragma unroll
  for (int q = 0; q < DTW; ++q) {
    int d0 = (w * DTW + q) * 16;
    afrag[q] = *(const bf16x8*)(amat + (size_t)(d0 + c) * 32 + g * 8);
    fet[q] = *(const f32x4*)(tab + (size_t)(t0 + c) * D_ + d0 + g * 4);
  }

  const f32x4 zac = {0.f, 0.f, 0.f, 0.f};
#pragma unroll
  for (int j = 0; j < 2; ++j) {
    int b = bg * 2 + j;
    bf16x8 bfrag;
    if (g < 3) {
      int row = (t0 + c + g - 1) & (T_ - 1);    // circular pad
      bfrag = *(const bf16x8*)(xbf + ((size_t)b * T_ + row) * 8);
    } else {
      bfrag = *(const bf16x8*)(cnt + ((size_t)b * T_ + t0 + c) * 8);
    }
#pragma unroll
    for (int q = 0; q < DTW; ++q) {
      f32x4 acc = __builtin_amdgcn_mfma_f32_16x16x32_bf16(
          afrag[q], bfrag, zac, 0, 0, 0);
      f32x4 ov;
      ov[0] = acc[0] + fet[q][0];               // w1=1, w0=0
      ov[1] = acc[1] + fet[q][1];
      ov[2] = acc[2] + fet[q][2];
      ov[3] = acc[3] + fet[q][3];
      int d0 = (w * DTW + q) * 16;
      *(f32x4*)(lds + c * LPAD + d0 + g * 4) = ov;
    }
    __syncthreads();
    float* obase = out + ((size_t)b * T_ + t0) * D_;
#pragma unroll
    for (int r = 0; r < 4; ++r) {
      int e = r * 2048 + tid * 4;
      int trow = e >> 9, col = e & 511;
      f32x4 v = *(const f32x4*)(lds + trow * LPAD + col);
      *(f32x4*)(obase + e) = v;
    }
    if (j == 0) __syncthreads();
  }
}

// ---- L3 fixup: 256 blocks x 1024 thr. Block j: batch b=j>>4, chunk=j&15
// (128 t-rows x 512 d). Computes m; if m==0 (the typical case) returns
// immediately. Else out += (-m/8)*FET[t][d] + (m/8) on odd d.
// Deterministic: m is a pure function of the fixed input.
__global__ __launch_bounds__(1024) void fixup_kernel(
    const float* __restrict__ pmax, const float* __restrict__ nyqS,
    const float* __restrict__ tab, float* __restrict__ out) {
  int j = blockIdx.x;
  int b = j >> 4;
  int chunk = j & 15;
  int m = 0;
#pragma unroll
  for (int nn = 0; nn < 8; ++nn) {
    int bn = b * 8 + nn;
    float mx = fmaxf(fmaxf(pmax[4 * bn], pmax[4 * bn + 1]),
                     fmaxf(pmax[4 * bn + 2], pmax[4 * bn + 3]));
    float S = nyqS[bn];
    if (S * S > mx) ++m;
  }
  if (m == 0) return;
  float wm = -(float)m * 0.125f;          // w1 - 1
  float w0 = (float)m * 0.125f;
  size_t obase = ((size_t)b * T_ + chunk * 128) * D_;
  size_t tbase = (size_t)(chunk * 128) * D_;
#pragma unroll
  for (int r = 0; r < 16; ++r) {
    size_t off = (size_t)(r * 1024 + threadIdx.x) * 4;
    f32x4 ov = *(f32x4*)(out + obase + off);
    f32x4 tv = *(const f32x4*)(tab + tbase + off);
    ov[0] = fmaf(wm, tv[0], ov[0]);
    ov[1] = fmaf(wm, tv[1], ov[1]) + w0;
    ov[2] = fmaf(wm, tv[2], ov[2]);
    ov[3] = fmaf(wm, tv[3], ov[3]) + w0;
    *(f32x4*)(out + obase + off) = ov;
  }
}

extern "C" void kernel_launch(void* const* d_in, const int* in_sizes, int n_in,
                              void* d_out, int out_size, void* d_ws, size_t ws_size,
                              hipStream_t stream) {
  const float* x = (const float*)d_in[0];
  const int* xmark = (const int*)d_in[1];
  const float* convw = (const float*)d_in[2];
  float* out = (float*)d_out;

  char* ws = (char*)d_ws;
  float* pmax = (float*)ws;                            // 512 f
  float* nyqS = pmax + 512;                            // 128 f
  float* tab = (float*)(ws + 4096);                    // 4 MB FET
  short* amat = (short*)(ws + 4096 + 4194304);         // 32 KB
  short* xbf = (short*)(ws + 4096 + 4194304 + 32768);  // 512 KB
  short* cnt = (short*)(ws + 4096 + 4194304 + 32768 + 524288);  // 512 KB

  prep_tail_kernel<<<161, 1024, 0, stream>>>(x, xmark, convw, tab, amat,
                                             xbf, cnt);
  fused_kernel<<<1536, 512, 0, stream>>>(x, amat, xbf, cnt, tab, pmax, nyqS,
                                         out);
  fixup_kernel<<<256, 1024, 0, stream>>>(pmax, nyqS, tab, out);
}

// Round 18
// 34.670 us; speedup vs baseline: 2.1749x; 1.1504x over previous
//
#include <hip/hip_runtime.h>
#include <math.h>

#define B_ 16
#define T_ 2048
#define N_ 8
#define D_ 512
#define DTW 4           // d-tiles (of 16) per wave
#define LPAD 520        // LDS row pitch (words)

// -2*pi/2048
#define NEG_W0 (-3.0679615757712823e-3f)
// -2*pi/32
#define NEG_W32 (-0.19634954084936207f)
// -2*pi/1024
#define NEG_W1024 (-6.1359231515425647e-3f)
// -2*ln(10000)/512
#define NEG_LDIV (-0.035977892078031555f)

typedef __attribute__((ext_vector_type(8))) short bf16x8;
typedef __attribute__((ext_vector_type(4))) float f32x4;

// fp32 -> bf16 (round-to-nearest-even)
static __device__ __forceinline__ short f2bf(float f) {
  unsigned int u = __float_as_uint(f);
  unsigned int r = u + 0x7FFFu + ((u >> 16) & 1u);
  return (short)(r >> 16);
}

// ws layout (byte offsets): [0,8192) pmax[1024]+nyqS[128];
// [8K,8K+4M) FET tab f32[2048][512]; amat bf16[512][32] (32 KB);
// xbf bf16[16][2048][8] (512 KB); cnt bf16[16][2048][8] (512 KB).
// All rewritten unconditionally every call (no init/protocol hazards).

// ---- prep: 1218 blocks x 256 thr — ALL small blocks, 6-8 blocks/CU, one
// scheduling round (fixes R15's 2-blocks/CU latency-bound prep wall).
//  blk 0..1023  : fft, block = (bn, parity, m1-quad h). Radix-32 two-stage
//                 folded DFT; stage 1 (all 1024 A) duplicated across the 4
//                 quad-siblings (one chain drives 4 t0-accumulators);
//                 stage 2 = this block's 4 m1 bins. pmax[blk] = partial
//                 max (8/bn, unconditional). nyqS[bn] from (parity0,h0).
//  blk 1024..1087: FET tabgen by rotation (R13-validated, 16-row strips)
//  blk 1088..1215: xbf + cnt rows
//  blk 1216..1217: amat
__global__ __launch_bounds__(256) void prep_kernel(
    const float* __restrict__ x, const int* __restrict__ xmark,
    const float* __restrict__ convw, float* __restrict__ pmax,
    float* __restrict__ nyqS, float* __restrict__ tab,
    short* __restrict__ amat, short* __restrict__ xbf,
    short* __restrict__ cnt) {
  int tid = threadIdx.x;
  int blk = blockIdx.x;

  if (blk >= 1024) {
    int j = blk - 1024;
    if (j < 64) {                         // ---- FET tabgen by rotation ----
      int gt = j * 256 + tid;             // 0..16383
      int tb = gt >> 7;                   // 16-row t-strip, 0..127
      int d4 = gt & 127;                  // float4 column
      float dv0 = expf((float)(d4 * 2) * NEG_LDIV);
      float dv1 = expf((float)(d4 * 2 + 1) * NEG_LDIV);
      float tf = (float)(tb * 16);
      float s0, c0, s1, c1, r0s, r0c, r1s, r1c;
      sincosf(tf * dv0, &s0, &c0);
      sincosf(tf * dv1, &s1, &c1);
      sincosf(dv0, &r0s, &r0c);           // small-arg fast path
      sincosf(dv1, &r1s, &r1c);
      float* row = tab + (size_t)(tb * 16) * D_ + d4 * 4;
#pragma unroll
      for (int u = 0; u < 16; ++u) {
        f32x4 v; v[0] = s0; v[1] = c0; v[2] = s1; v[3] = c1;
        *(f32x4*)row = v;
        row += D_;
        float ns0 = fmaf(s0, r0c, c0 * r0s), nc0 = fmaf(c0, r0c, -s0 * r0s);
        s0 = ns0; c0 = nc0;
        float ns1 = fmaf(s1, r1c, c1 * r1s), nc1 = fmaf(c1, r1c, -s1 * r1s);
        s1 = ns1; c1 = nc1;
      }
    } else if (j < 192) {                 // ---- xbf + cnt rows ----
      int r = (j - 64) * 256 + tid;       // r = b*T + t, 0..32767
      const float4* xr = (const float4*)(x + (size_t)r * 8);
      float4 lo = xr[0], hi = xr[1];
      bf16x8 v;
      v[0] = f2bf(lo.x); v[1] = f2bf(lo.y); v[2] = f2bf(lo.z); v[3] = f2bf(lo.w);
      v[4] = f2bf(hi.x); v[5] = f2bf(hi.y); v[6] = f2bf(hi.z); v[7] = f2bf(hi.w);
      *(bf16x8*)(xbf + (size_t)r * 8) = v;
      int4 mk = *(const int4*)(xmark + (size_t)r * 4);
      bf16x8 cv;
#pragma unroll
      for (int p = 0; p < 8; ++p) {
        int cc = (mk.x == p) + (mk.y == p) + (mk.z == p) + (mk.w == p);
        cv[p] = f2bf((float)cc);
      }
      *(bf16x8*)(cnt + (size_t)r * 8) = cv;
    } else {                              // ---- amat (2 blocks) ----
      int d = (j - 192) * 256 + tid;      // 0..511
      short row[32];
#pragma unroll
      for (int kk = 0; kk < 24; ++kk) {
        int g = kk >> 3, n = kk & 7;      // A[d][g*8+n] = W[d][n][k=g]
        row[kk] = f2bf(convw[d * 24 + n * 3 + g]);
      }
      float divv = expf((float)(d >> 1) * NEG_LDIV);
      float s1, c1;
      sincosf(divv, &s1, &c1);
      int odd = d & 1;
      row[24] = f2bf(odd ? 1.f : 0.f);
      float ps = s1, pc = c1;
      row[25] = f2bf(odd ? pc : ps);
#pragma unroll
      for (int p = 2; p < 7; ++p) {
        float ns = fmaf(ps, c1, pc * s1);
        float nc = fmaf(pc, c1, -ps * s1);
        ps = ns; pc = nc;
        row[24 + p] = f2bf(odd ? pc : ps);
      }
      row[31] = 0;                        // marks < 7
#pragma unroll
      for (int q = 0; q < 4; ++q)
        *(bf16x8*)(amat + d * 32 + q * 8) = *(bf16x8*)&row[q * 8];
    }
    return;
  }

  // ---- fft: block = (bn, parity, h); 256 threads ----
  __shared__ __align__(16) float2 ybuf[1024];  // parity0: first half = float[1024]
  __shared__ __align__(16) float2 Bl[1024];
  __shared__ __align__(16) float2 part[256];
  __shared__ float swav[4];
  __shared__ float pwav[2];
  int bn = blk >> 3;
  int parity = (blk >> 2) & 1;
  int h = blk & 3;
  int b = bn >> 3, n = bn & 7;
  const float* xb = x + (size_t)b * (T_ * N_) + n;

  // load 4 (e,o) pairs: t = tid + j*256
  float ev[4], ov[4];
  float esum = 0.f;
#pragma unroll
  for (int j = 0; j < 4; ++j) {
    int t = tid + j * 256;
    float va = xb[t * 8];
    float vb = xb[(t + 1024) * 8];
    ev[j] = va + vb;
    ov[j] = va - vb;
    esum += ev[j];
  }
  // Nyquist partial: (-1)^t e_t ; all 4 t share parity of tid
  float sgn = (tid & 1) ? -esum : esum;
#pragma unroll
  for (int off = 32; off > 0; off >>= 1) sgn += __shfl_down(sgn, off);
  if ((tid & 63) == 0) swav[tid >> 6] = sgn;

  if (parity == 0) {
    float* ya = (float*)ybuf;
#pragma unroll
    for (int j = 0; j < 4; ++j) ya[tid + j * 256] = ev[j];
  } else {
#pragma unroll
    for (int j = 0; j < 4; ++j) {
      int t = tid + j * 256;
      float c0, s0;
      sincosf((float)t * NEG_W0, &s0, &c0);
      ybuf[t] = make_float2(ov[j] * c0, ov[j] * s0);
    }
  }
  __syncthreads();

  // ---- stage 1: thread (t0g = tid>>5 in [0,8), m0 = tid&31) computes A
  //      for t0 = t0g*4..t0g*4+3 sharing ONE Chebyshev chain ----
  int m0 = tid & 31, t0g = tid >> 5;
  float d1 = (float)m0 * NEG_W32;
  float K1 = 2.0f * cosf(d1);
  float c = 1.f, s = 0.f, cp, sp;
  sincosf(-d1, &sp, &cp);                 // angle at t1 = -1
  float ar[4] = {0.f, 0.f, 0.f, 0.f}, ai[4] = {0.f, 0.f, 0.f, 0.f};
  if (parity == 0) {
    const float4* ya4 = (const float4*)ybuf;  // ya as float4[256]
#pragma unroll 8
    for (int t1 = 0; t1 < 32; ++t1) {
      float4 y = ya4[t1 * 8 + t0g];       // half-wave broadcast
      ar[0] = fmaf(y.x, c, ar[0]); ai[0] = fmaf(y.x, s, ai[0]);
      ar[1] = fmaf(y.y, c, ar[1]); ai[1] = fmaf(y.y, s, ai[1]);
      ar[2] = fmaf(y.z, c, ar[2]); ai[2] = fmaf(y.z, s, ai[2]);
      ar[3] = fmaf(y.w, c, ar[3]); ai[3] = fmaf(y.w, s, ai[3]);
      float nc = fmaf(K1, c, -cp), ns = fmaf(K1, s, -sp);
      cp = c; sp = s; c = nc; s = ns;
    }
  } else {
    const float4* yb4 = (const float4*)ybuf;  // float2 pairs
#pragma unroll 8
    for (int t1 = 0; t1 < 32; ++t1) {
      float4 p0 = yb4[t1 * 16 + t0g * 2];      // y[t0g*4+0], y[t0g*4+1]
      float4 p1 = yb4[t1 * 16 + t0g * 2 + 1];  // y[t0g*4+2], y[t0g*4+3]
      ar[0] = fmaf(p0.x, c, fmaf(-p0.y, s, ar[0]));
      ai[0] = fmaf(p0.x, s, fmaf(p0.y, c, ai[0]));
      ar[1] = fmaf(p0.z, c, fmaf(-p0.w, s, ar[1]));
      ai[1] = fmaf(p0.z, s, fmaf(p0.w, c, ai[1]));
      ar[2] = fmaf(p1.x, c, fmaf(-p1.y, s, ar[2]));
      ai[2] = fmaf(p1.x, s, fmaf(p1.y, c, ai[2]));
      ar[3] = fmaf(p1.z, c, fmaf(-p1.w, s, ar[3]));
      ai[3] = fmaf(p1.z, s, fmaf(p1.w, c, ai[3]));
      float nc = fmaf(K1, c, -cp), ns = fmaf(K1, s, -sp);
      cp = c; sp = s; c = nc; s = ns;
    }
  }
  // fine twiddle W1024^{t0*m0} and store B
#pragma unroll
  for (int j = 0; j < 4; ++j) {
    int t0 = t0g * 4 + j;
    float ct, st;
    sincosf((float)(t0 * m0) * NEG_W1024, &st, &ct);
    Bl[t0 * 32 + m0] =
        make_float2(ar[j] * ct - ai[j] * st, fmaf(ar[j], st, ai[j] * ct));
  }
  __syncthreads();

  // ---- stage 2: this block's 4 m1 = h*4 + (tid>>5)&3; 2 threads/bin
  //      over t0-halves (th = tid>>7) ----
  int m02 = tid & 31;
  int m1 = h * 4 + ((tid >> 5) & 3);
  int th = tid >> 7;                      // 0/1
  float d2 = (float)m1 * NEG_W32;
  float K2 = 2.0f * cosf(d2);
  int t0s = th * 16;
  float c2, s2, c2p, s2p;
  sincosf((float)t0s * d2, &s2, &c2);
  sincosf((float)(t0s - 1) * d2, &s2p, &c2p);
  float yr = 0.f, yi = 0.f;
#pragma unroll 8
  for (int jj = 0; jj < 16; ++jj) {
    float2 bv = Bl[(t0s + jj) * 32 + m02];
    yr = fmaf(bv.x, c2, fmaf(-bv.y, s2, yr));
    yi = fmaf(bv.x, s2, fmaf(bv.y, c2, yi));
    float nc = fmaf(K2, c2, -c2p), ns = fmaf(K2, s2, -s2p);
    c2p = c2; s2p = s2; c2 = nc; s2 = ns;
  }
  part[tid] = make_float2(yr, yi);
  __syncthreads();
  if (tid < 128) {
    float2 pa = part[tid], pb = part[tid + 128];  // combine t0-halves
    float rr = pa.x + pb.x, ii = pa.y + pb.y;
    float P = fmaf(rr, rr, ii * ii);
#pragma unroll
    for (int off = 32; off > 0; off >>= 1) P = fmaxf(P, __shfl_down(P, off));
    if ((tid & 63) == 0) pwav[tid >> 6] = P;
  }
  __syncthreads();
  if (tid == 0) {
    pmax[blk] = fmaxf(pwav[0], pwav[1]);  // unconditional plain store
    if (parity == 0 && h == 0)
      nyqS[bn] = swav[0] + swav[1] + swav[2] + swav[3];
  }
}

// ---- main (R15 body — at HBM roofline per R16: 11.3 us/replica):
// MFMA (conv slots 0..23 + temporal 24..31) -> LDS repack -> 4 x 8 KB
// sequential store rounds. Block = 16-row t-tile x 512 d x 2 batches.
// Only change vs R15: pmax has 8 partials per bn.
__global__ __launch_bounds__(512, 6) void main_kernel(
    const short* __restrict__ amat, const short* __restrict__ xbf,
    const short* __restrict__ cnt, const float* __restrict__ tab,
    const float* __restrict__ pmax, const float* __restrict__ nyqS,
    float* __restrict__ out) {
  __shared__ __align__(16) float lds[16 * LPAD];
  int tid = threadIdx.x;
  int lane = tid & 63;
  int w = tid >> 6;
  int c = lane & 15;
  int g = lane >> 4;
  int blk = blockIdx.x;
  int ttile = blk & 127;
  int bg = blk >> 7;
  int t0 = ttile * 16;

  float w1v[2], w0v[2];
#pragma unroll
  for (int j = 0; j < 2; ++j) {
    int b = bg * 2 + j;
    int m = 0;
#pragma unroll
    for (int nn = 0; nn < 8; ++nn) {
      int bn = b * 8 + nn;
      float mx = 0.f;
#pragma unroll
      for (int k = 0; k < 8; ++k) mx = fmaxf(mx, pmax[8 * bn + k]);
      float S = nyqS[bn];
      if (S * S > mx) ++m;
    }
    w1v[j] = (float)(8 - m) * 0.125f;
    w0v[j] = (float)m * 0.125f;
  }

  bf16x8 afrag[DTW];
  f32x4 fet[DTW];
#pragma unroll
  for (int q = 0; q < DTW; ++q) {
    int d0 = (w * DTW + q) * 16;
    afrag[q] = *(const bf16x8*)(amat + (size_t)(d0 + c) * 32 + g * 8);
    fet[q] = *(const f32x4*)(tab + (size_t)(t0 + c) * D_ + d0 + g * 4);
  }

  const f32x4 zac = {0.f, 0.f, 0.f, 0.f};
#pragma unroll
  for (int j = 0; j < 2; ++j) {
    int b = bg * 2 + j;
    bf16x8 bfrag;
    if (g < 3) {
      int row = (t0 + c + g - 1) & (T_ - 1);    // circular pad
      bfrag = *(const bf16x8*)(xbf + ((size_t)b * T_ + row) * 8);
    } else {
      bfrag = *(const bf16x8*)(cnt + ((size_t)b * T_ + t0 + c) * 8);
    }
    float w1 = w1v[j], w0 = w0v[j];
#pragma unroll
    for (int q = 0; q < DTW; ++q) {
      f32x4 acc = __builtin_amdgcn_mfma_f32_16x16x32_bf16(
          afrag[q], bfrag, zac, 0, 0, 0);
      f32x4 ov;
      ov[0] = fmaf(w1, fet[q][0], acc[0]);
      ov[1] = fmaf(w1, fet[q][1], acc[1]) + w0;
      ov[2] = fmaf(w1, fet[q][2], acc[2]);
      ov[3] = fmaf(w1, fet[q][3], acc[3]) + w0;
      int d0 = (w * DTW + q) * 16;
      *(f32x4*)(lds + c * LPAD + d0 + g * 4) = ov;
    }
    __syncthreads();
    float* obase = out + ((size_t)b * T_ + t0) * D_;
#pragma unroll
    for (int r = 0; r < 4; ++r) {
      int e = r * 2048 + tid * 4;
      int trow = e >> 9, col = e & 511;
      f32x4 v = *(const f32x4*)(lds + trow * LPAD + col);
      *(f32x4*)(obase + e) = v;
    }
    if (j == 0) __syncthreads();
  }
}

extern "C" void kernel_launch(void* const* d_in, const int* in_sizes, int n_in,
                              void* d_out, int out_size, void* d_ws, size_t ws_size,
                              hipStream_t stream) {
  const float* x = (const float*)d_in[0];
  const int* xmark = (const int*)d_in[1];
  const float* convw = (const float*)d_in[2];
  float* out = (float*)d_out;

  char* ws = (char*)d_ws;
  float* pmax = (float*)ws;                            // 1024 f
  float* nyqS = pmax + 1024;                           // 128 f
  float* tab = (float*)(ws + 8192);                    // 4 MB FET
  short* amat = (short*)(ws + 8192 + 4194304);         // 32 KB
  short* xbf = (short*)(ws + 8192 + 4194304 + 32768);  // 512 KB
  short* cnt = (short*)(ws + 8192 + 4194304 + 32768 + 524288);  // 512 KB

  prep_kernel<<<1218, 256, 0, stream>>>(x, xmark, convw, pmax, nyqS, tab,
                                        amat, xbf, cnt);
  main_kernel<<<(T_ / 16) * (B_ / 2), 512, 0, stream>>>(amat, xbf, cnt, tab,
                                                        pmax, nyqS, out);
}

// Round 19
// 34.157 us; speedup vs baseline: 2.2075x; 1.0150x over previous
//
#include <hip/hip_runtime.h>
#include <math.h>

#define B_ 16
#define T_ 2048
#define N_ 8
#define D_ 512
#define DTW 4           // d-tiles (of 16) per wave
#define LPAD 520        // LDS row pitch (words)

// -pi/1024 ( = -2*pi/2048 )
#define NEG_W0 (-3.0679615757712823e-3f)
// -2*ln(10000)/512
#define NEG_LDIV (-0.035977892078031555f)

typedef __attribute__((ext_vector_type(8))) short bf16x8;
typedef __attribute__((ext_vector_type(4))) float f32x4;

// fp32 -> bf16 (round-to-nearest-even)
static __device__ __forceinline__ short f2bf(float f) {
  unsigned int u = __float_as_uint(f);
  unsigned int r = u + 0x7FFFu + ((u >> 16) & 1u);
  return (short)(r >> 16);
}

// ws layout (byte offsets):
//   [0,2048)       pmax[512]  (4 partials per bn: bn*4 + parity*2 + h)
//   [2048,8192)    nyqS[128]
//   [8K, 8K+4M)    FET tab f32[2048][512]
//   +4M..          amat bf16[512][32] (32 KB)
//   ..             xbf bf16[16][2048][8] (512 KB)
//   ..             cnt bf16[16][2048][8] (512 KB)
//   5283840..      Bws float2[128][2][32][32] (2 MB) stage-1 -> stage-2
// All rewritten unconditionally every call; cross-kernel hand-off only
// through launch boundaries (no intra-launch protocols).

// ---- L1: 1218 blocks x 256 thr.
//  blk 0..1023 : fft stage 1. block = (bn, parity, m0-quad q). Uniform
//    Cooley-Tukey: k = 2m+parity, m = 32*m1+m0, km = 2*m0+parity.
//    A[t0][m0] = sum_{t1<32} y[32t1+t0] * e^{-i pi km t1/32}  (y real!)
//    B[m0][t0] = A * e^{i NEG_W0 t0 km}; thread = (m0 = q*8+(tid>>5),
//    t0 = tid&31), ONE Chebyshev chain each — no duplicated work.
//    parity0/q0 blocks also reduce nyqS = sum (-1)^t e_t.
//  blk 1024..1087: FET tabgen by rotation (R18-validated)
//  blk 1088..1215: xbf + cnt rows
//  blk 1216..1217: amat
__global__ __launch_bounds__(256) void prep1_kernel(
    const float* __restrict__ x, const int* __restrict__ xmark,
    const float* __restrict__ convw, float* __restrict__ nyqS,
    float* __restrict__ tab, short* __restrict__ amat,
    short* __restrict__ xbf, short* __restrict__ cnt,
    float2* __restrict__ Bws) {
  int tid = threadIdx.x;
  int blk = blockIdx.x;

  if (blk >= 1024) {
    int j = blk - 1024;
    if (j < 64) {                         // ---- FET tabgen by rotation ----
      int gt = j * 256 + tid;             // 0..16383
      int tb = gt >> 7;                   // 16-row t-strip
      int d4 = gt & 127;
      float dv0 = expf((float)(d4 * 2) * NEG_LDIV);
      float dv1 = expf((float)(d4 * 2 + 1) * NEG_LDIV);
      float tf = (float)(tb * 16);
      float s0, c0, s1, c1, r0s, r0c, r1s, r1c;
      sincosf(tf * dv0, &s0, &c0);
      sincosf(tf * dv1, &s1, &c1);
      sincosf(dv0, &r0s, &r0c);
      sincosf(dv1, &r1s, &r1c);
      float* row = tab + (size_t)(tb * 16) * D_ + d4 * 4;
#pragma unroll
      for (int u = 0; u < 16; ++u) {
        f32x4 v; v[0] = s0; v[1] = c0; v[2] = s1; v[3] = c1;
        *(f32x4*)row = v;
        row += D_;
        float ns0 = fmaf(s0, r0c, c0 * r0s), nc0 = fmaf(c0, r0c, -s0 * r0s);
        s0 = ns0; c0 = nc0;
        float ns1 = fmaf(s1, r1c, c1 * r1s), nc1 = fmaf(c1, r1c, -s1 * r1s);
        s1 = ns1; c1 = nc1;
      }
    } else if (j < 192) {                 // ---- xbf + cnt rows ----
      int r = (j - 64) * 256 + tid;       // r = b*T + t
      const float4* xr = (const float4*)(x + (size_t)r * 8);
      float4 lo = xr[0], hi = xr[1];
      bf16x8 v;
      v[0] = f2bf(lo.x); v[1] = f2bf(lo.y); v[2] = f2bf(lo.z); v[3] = f2bf(lo.w);
      v[4] = f2bf(hi.x); v[5] = f2bf(hi.y); v[6] = f2bf(hi.z); v[7] = f2bf(hi.w);
      *(bf16x8*)(xbf + (size_t)r * 8) = v;
      int4 mk = *(const int4*)(xmark + (size_t)r * 4);
      bf16x8 cv;
#pragma unroll
      for (int p = 0; p < 8; ++p) {
        int cc = (mk.x == p) + (mk.y == p) + (mk.z == p) + (mk.w == p);
        cv[p] = f2bf((float)cc);
      }
      *(bf16x8*)(cnt + (size_t)r * 8) = cv;
    } else {                              // ---- amat (2 blocks) ----
      int d = (j - 192) * 256 + tid;      // 0..511
      short row[32];
#pragma unroll
      for (int kk = 0; kk < 24; ++kk) {
        int g = kk >> 3, n = kk & 7;      // A[d][g*8+n] = W[d][n][k=g]
        row[kk] = f2bf(convw[d * 24 + n * 3 + g]);
      }
      float divv = expf((float)(d >> 1) * NEG_LDIV);
      float s1, c1;
      sincosf(divv, &s1, &c1);
      int odd = d & 1;
      row[24] = f2bf(odd ? 1.f : 0.f);
      float ps = s1, pc = c1;
      row[25] = f2bf(odd ? pc : ps);
#pragma unroll
      for (int p = 2; p < 7; ++p) {
        float ns = fmaf(ps, c1, pc * s1);
        float nc = fmaf(pc, c1, -ps * s1);
        ps = ns; pc = nc;
        row[24 + p] = f2bf(odd ? pc : ps);
      }
      row[31] = 0;                        // marks < 7
#pragma unroll
      for (int q = 0; q < 4; ++q)
        *(bf16x8*)(amat + d * 32 + q * 8) = *(bf16x8*)&row[q * 8];
    }
    return;
  }

  // ---- fft stage 1 ----
  __shared__ __align__(16) float y[1024];
  __shared__ float swred[4];
  int bn = blk >> 3;
  int parity = (blk >> 2) & 1;
  int q = blk & 3;
  int b = bn >> 3, n = bn & 7;
  const float* xb = x + (size_t)b * (T_ * N_) + n;

  float sloc = 0.f;
#pragma unroll
  for (int j = 0; j < 4; ++j) {
    int t = tid + j * 256;
    float va = xb[t * 8];
    float vb = xb[(t + 1024) * 8];
    float yv = parity ? (va - vb) : (va + vb);
    y[t] = yv;
    sloc += yv;
  }
  // Nyquist partial (-1)^t y_t (meaningful for parity 0); t parity == tid&1
  float sgn = (tid & 1) ? -sloc : sloc;
#pragma unroll
  for (int off = 32; off > 0; off >>= 1) sgn += __shfl_down(sgn, off);
  if ((tid & 63) == 0) swred[tid >> 6] = sgn;
  __syncthreads();

  int m0 = q * 8 + (tid >> 5);
  int t0 = tid & 31;
  int km = 2 * m0 + parity;               // 0..63
  float step = (float)(32 * km) * NEG_W0; // -(pi/32)*km
  float cst, sst;
  sincosf(step, &sst, &cst);
  float K = 2.f * cst;
  float c = 1.f, s = 0.f, cp = cst, sp = -sst;   // angle at t1 = -1
  float ar = 0.f, ai = 0.f;
#pragma unroll 8
  for (int t1 = 0; t1 < 32; ++t1) {
    float yv = y[t1 * 32 + t0];           // same addr across m0-groups
    ar = fmaf(yv, c, ar);
    ai = fmaf(yv, s, ai);
    float nc = fmaf(K, c, -cp), ns = fmaf(K, s, -sp);
    cp = c; sp = s; c = nc; s = ns;
  }
  float af = (float)(t0 * km) * NEG_W0;   // fine twiddle
  float sf, cf;
  sincosf(af, &sf, &cf);
  float2 Bv = make_float2(ar * cf - ai * sf, fmaf(ar, sf, ai * cf));
  Bws[((size_t)(bn * 2 + parity) * 32 + m0) * 32 + t0] = Bv;

  if (tid == 0 && parity == 0 && q == 0)
    nyqS[bn] = swred[0] + swred[1] + swred[2] + swred[3];
}

// ---- L2: fft stage 2. 512 blocks x 256 thr: block = (bn, parity, h).
// X[m1][m0] = sum_{t0<32} B[m0][t0] * e^{-i (pi/16) m1 t0}; thread = one
// bin (m1 = h*8 + tid>>5, m0 = tid&31). pmax[blk] = block max of |X|^2.
__global__ __launch_bounds__(256) void stage2_kernel(
    const float2* __restrict__ Bws, float* __restrict__ pmax) {
  __shared__ __align__(16) float2 Bs[32 * 33];   // padded: 2-way free
  __shared__ float pw[4];
  int tid = threadIdx.x;
  int blk = blockIdx.x;
  int bn = blk >> 2;
  int parity = (blk >> 1) & 1;
  int h = blk & 1;
  const float2* Bg = Bws + (size_t)(bn * 2 + parity) * 1024;
#pragma unroll
  for (int j = 0; j < 4; ++j) {
    int idx = tid + j * 256;              // idx = m0*32 + t0
    Bs[(idx >> 5) * 33 + (idx & 31)] = Bg[idx];
  }
  __syncthreads();

  int m0 = tid & 31;
  int m1 = h * 8 + (tid >> 5);
  float step = (float)(64 * m1) * NEG_W0; // -(pi/16)*m1
  float cst, sst;
  sincosf(step, &sst, &cst);
  float K = 2.f * cst;
  float c = 1.f, s = 0.f, cp = cst, sp = -sst;
  float yr = 0.f, yi = 0.f;
#pragma unroll 8
  for (int t0 = 0; t0 < 32; ++t0) {
    float2 bv = Bs[m0 * 33 + t0];
    yr = fmaf(bv.x, c, fmaf(-bv.y, s, yr));
    yi = fmaf(bv.x, s, fmaf(bv.y, c, yi));
    float nc = fmaf(K, c, -cp), ns = fmaf(K, s, -sp);
    cp = c; sp = s; c = nc; s = ns;
  }
  float P = fmaf(yr, yr, yi * yi);
#pragma unroll
  for (int off = 32; off > 0; off >>= 1) P = fmaxf(P, __shfl_down(P, off));
  if ((tid & 63) == 0) pw[tid >> 6] = P;
  __syncthreads();
  if (tid == 0)
    pmax[blk] = fmaxf(fmaxf(pw[0], pw[1]), fmaxf(pw[2], pw[3]));
}

// ---- L3 main (R15 body — HBM-roofline per R16): MFMA (conv slots 0..23 +
// temporal 24..31) -> LDS repack -> 4 x 8 KB sequential store rounds.
// Block = 16-row t-tile x 512 d x 2 batches; pmax now 4 partials per bn.
__global__ __launch_bounds__(512, 6) void main_kernel(
    const short* __restrict__ amat, const short* __restrict__ xbf,
    const short* __restrict__ cnt, const float* __restrict__ tab,
    const float* __restrict__ pmax, const float* __restrict__ nyqS,
    float* __restrict__ out) {
  __shared__ __align__(16) float lds[16 * LPAD];
  int tid = threadIdx.x;
  int lane = tid & 63;
  int w = tid >> 6;
  int c = lane & 15;
  int g = lane >> 4;
  int blk = blockIdx.x;
  int ttile = blk & 127;
  int bg = blk >> 7;
  int t0 = ttile * 16;

  float w1v[2], w0v[2];
#pragma unroll
  for (int j = 0; j < 2; ++j) {
    int b = bg * 2 + j;
    int m = 0;
#pragma unroll
    for (int nn = 0; nn < 8; ++nn) {
      int bn = b * 8 + nn;
      float mx = fmaxf(fmaxf(pmax[4 * bn], pmax[4 * bn + 1]),
                       fmaxf(pmax[4 * bn + 2], pmax[4 * bn + 3]));
      float S = nyqS[bn];
      if (S * S > mx) ++m;
    }
    w1v[j] = (float)(8 - m) * 0.125f;
    w0v[j] = (float)m * 0.125f;
  }

  bf16x8 afrag[DTW];
  f32x4 fet[DTW];
#pragma unroll
  for (int q = 0; q < DTW; ++q) {
    int d0 = (w * DTW + q) * 16;
    afrag[q] = *(const bf16x8*)(amat + (size_t)(d0 + c) * 32 + g * 8);
    fet[q] = *(const f32x4*)(tab + (size_t)(t0 + c) * D_ + d0 + g * 4);
  }

  const f32x4 zac = {0.f, 0.f, 0.f, 0.f};
#pragma unroll
  for (int j = 0; j < 2; ++j) {
    int b = bg * 2 + j;
    bf16x8 bfrag;
    if (g < 3) {
      int row = (t0 + c + g - 1) & (T_ - 1);    // circular pad
      bfrag = *(const bf16x8*)(xbf + ((size_t)b * T_ + row) * 8);
    } else {
      bfrag = *(const bf16x8*)(cnt + ((size_t)b * T_ + t0 + c) * 8);
    }
    float w1 = w1v[j], w0 = w0v[j];
#pragma unroll
    for (int q = 0; q < DTW; ++q) {
      f32x4 acc = __builtin_amdgcn_mfma_f32_16x16x32_bf16(
          afrag[q], bfrag, zac, 0, 0, 0);
      f32x4 ov;
      ov[0] = fmaf(w1, fet[q][0], acc[0]);
      ov[1] = fmaf(w1, fet[q][1], acc[1]) + w0;
      ov[2] = fmaf(w1, fet[q][2], acc[2]);
      ov[3] = fmaf(w1, fet[q][3], acc[3]) + w0;
      int d0 = (w * DTW + q) * 16;
      *(f32x4*)(lds + c * LPAD + d0 + g * 4) = ov;
    }
    __syncthreads();
    float* obase = out + ((size_t)b * T_ + t0) * D_;
#pragma unroll
    for (int r = 0; r < 4; ++r) {
      int e = r * 2048 + tid * 4;
      int trow = e >> 9, col = e & 511;
      f32x4 v = *(const f32x4*)(lds + trow * LPAD + col);
      *(f32x4*)(obase + e) = v;
    }
    if (j == 0) __syncthreads();
  }
}

extern "C" void kernel_launch(void* const* d_in, const int* in_sizes, int n_in,
                              void* d_out, int out_size, void* d_ws, size_t ws_size,
                              hipStream_t stream) {
  const float* x = (const float*)d_in[0];
  const int* xmark = (const int*)d_in[1];
  const float* convw = (const float*)d_in[2];
  float* out = (float*)d_out;

  char* ws = (char*)d_ws;
  float* pmax = (float*)ws;                            // 512 f
  float* nyqS = (float*)(ws + 2048);                   // 128 f
  float* tab = (float*)(ws + 8192);                    // 4 MB FET
  short* amat = (short*)(ws + 8192 + 4194304);         // 32 KB
  short* xbf = (short*)(ws + 8192 + 4194304 + 32768);  // 512 KB
  short* cnt = (short*)(ws + 8192 + 4194304 + 32768 + 524288);  // 512 KB
  float2* Bws = (float2*)(ws + 8192 + 4194304 + 32768 + 524288 + 524288);

  prep1_kernel<<<1218, 256, 0, stream>>>(x, xmark, convw, nyqS, tab, amat,
                                         xbf, cnt, Bws);
  stage2_kernel<<<512, 256, 0, stream>>>(Bws, pmax);
  main_kernel<<<(T_ / 16) * (B_ / 2), 512, 0, stream>>>(amat, xbf, cnt, tab,
                                                        pmax, nyqS, out);
}

// Round 20
// 27.114 us; speedup vs baseline: 2.7809x; 1.2598x over previous
//
#include <hip/hip_runtime.h>
#include <math.h>

#define B_ 16
#define T_ 2048
#define N_ 8
#define D_ 512
#define DTW 4           // d-tiles (of 16) per wave
#define LPAD 520        // LDS row pitch (words)

// -pi/1024 ( = -2*pi/2048 )
#define NEG_W0 (-3.0679615757712823e-3f)
// -2*ln(10000)/512
#define NEG_LDIV (-0.035977892078031555f)

typedef __attribute__((ext_vector_type(8))) short bf16x8;
typedef __attribute__((ext_vector_type(4))) float f32x4;

// fp32 -> bf16 (round-to-nearest-even)
static __device__ __forceinline__ short f2bf(float f) {
  unsigned int u = __float_as_uint(f);
  unsigned int r = u + 0x7FFFu + ((u >> 16) & 1u);
  return (short)(r >> 16);
}

// ws layout (byte offsets): [0,512) pmax[128] (ONE value per bn);
// [2048,2560) nyqS[128]; [8K,8K+4M) FET tab f32[2048][512];
// +4M: amat bf16[512][32] (32 KB); xbf bf16[16][2048][8] (512 KB);
// cnt bf16[16][2048][8] (512 KB). All rewritten unconditionally every call.

// ---- prep: 225 blocks x 512 thr, one scheduling round.
//  blk 0..127 : per-(b,n) spectrum. Real-2048 DFT via complex 1024-pt
//    radix-2 DIT FFT of z_t = x_{2t} + i x_{2t+1} (LDS, 10 stages, table
//    twiddles, index-padded vs bank conflicts), then per-thread untangle
//    X_k = E_k + w^k O_k for k=j and k=1024-j. Nyquist X_1024 =
//    Re(Z_0)-Im(Z_0). Single writer: pmax[bn] = max_{k<1024}|X_k|^2,
//    nyqS[bn] = X_1024. Serial depth ~10 barriers (vs 64-step chains).
//  blk 128..159: FET tabgen by rotation (R13/R18-validated)
//  blk 160..223: xbf + cnt rows
//  blk 224     : amat
__global__ __launch_bounds__(512) void prep_kernel(
    const float* __restrict__ x, const int* __restrict__ xmark,
    const float* __restrict__ convw, float* __restrict__ pmax,
    float* __restrict__ nyqS, float* __restrict__ tab,
    short* __restrict__ amat, short* __restrict__ xbf,
    short* __restrict__ cnt) {
  __shared__ __align__(16) float2 zs[1088];   // 1024 + pad(i>>4)
  __shared__ __align__(16) float2 tws[544];   // 512 + pad
  __shared__ float red[8];
  int tid = threadIdx.x;
  int blk = blockIdx.x;

  if (blk < 128) {
    // ---- fft role ----
    int bn = blk;
    int b = bn >> 3, n = bn & 7;
    const float* xb = x + (size_t)b * (T_ * N_) + n;

    {  // twiddle table: tws[i] = e^{-2pi i k/1024}
      float ss, cc;
      sincosf((float)tid * (2.0f * NEG_W0), &ss, &cc);
      tws[tid + (tid >> 4)] = make_float2(cc, ss);
    }
#pragma unroll
    for (int u = 0; u < 2; ++u) {   // load, bit-reversed placement
      int tau = tid + u * 512;
      float re = xb[(2 * tau) * 8];
      float im = xb[(2 * tau + 1) * 8];
      int p = __brev(tau) >> 22;    // 10-bit reversal
      zs[p + (p >> 4)] = make_float2(re, im);
    }
    __syncthreads();

#pragma unroll
    for (int s = 1; s <= 10; ++s) { // radix-2 DIT stages
      int half = 1 << (s - 1);
      int idx = tid & (half - 1);
      int grp = tid >> (s - 1);
      int p0 = grp * (half << 1) + idx;
      int p1 = p0 + half;
      int ti = idx << (10 - s);
      float2 tw = tws[ti + (ti >> 4)];
      float2 a = zs[p0 + (p0 >> 4)];
      float2 bv = zs[p1 + (p1 >> 4)];
      float tr = bv.x * tw.x - bv.y * tw.y;
      float tq = fmaf(bv.x, tw.y, bv.y * tw.x);
      zs[p1 + (p1 >> 4)] = make_float2(a.x - tr, a.y - tq);
      zs[p0 + (p0 >> 4)] = make_float2(a.x + tr, a.y + tq);
      __syncthreads();
    }

    // untangle: thread j covers bins k=j and k=1024-j
    int j = tid;
    int jm = (1024 - j) & 1023;
    float2 A = zs[j + (j >> 4)];
    float2 Bv = zs[jm + (jm >> 4)];
    float u = A.x - Bv.x, v = A.y + Bv.y;
    float Ere = 0.5f * (A.x + Bv.x), Eim = 0.5f * (A.y - Bv.y);
    float Ore = 0.5f * v, Oim = -0.5f * u;
    float cw, sw;
    sincosf((float)j * NEG_W0, &sw, &cw);
    float Gr = Ere + cw * Ore - sw * Oim;       // X_j
    float Gi = Eim + cw * Oim + sw * Ore;
    float P = fmaf(Gr, Gr, Gi * Gi);
    float Gpr = Ere - cw * Ore + sw * Oim;      // X_{1024-j}
    float Gpi = -Eim + cw * Oim + sw * Ore;
    float P2;
    if (j == 0) {
      // Gpr here is X_1024 = ReZ0 - ImZ0 (Nyquist; excluded from max)
      nyqS[bn] = Gpr;
      float2 Am = zs[512 + (512 >> 4)];         // k=512: X = conj(Z_512)
      P2 = fmaf(Am.x, Am.x, Am.y * Am.y);
    } else {
      P2 = fmaf(Gpr, Gpr, Gpi * Gpi);
    }
    P = fmaxf(P, P2);
#pragma unroll
    for (int off = 32; off > 0; off >>= 1) P = fmaxf(P, __shfl_down(P, off));
    if ((tid & 63) == 0) red[tid >> 6] = P;
    __syncthreads();
    if (tid == 0) {
      float mx = red[0];
#pragma unroll
      for (int k = 1; k < 8; ++k) mx = fmaxf(mx, red[k]);
      pmax[bn] = mx;                            // single unconditional writer
    }
    return;
  }

  int j = blk - 128;
  if (j < 32) {                         // ---- FET tabgen by rotation ----
    int gt = j * 512 + tid;             // 0..16383
    int tb = gt >> 7;                   // 16-row t-strip
    int d4 = gt & 127;
    float dv0 = expf((float)(d4 * 2) * NEG_LDIV);
    float dv1 = expf((float)(d4 * 2 + 1) * NEG_LDIV);
    float tf = (float)(tb * 16);
    float s0, c0, s1, c1, r0s, r0c, r1s, r1c;
    sincosf(tf * dv0, &s0, &c0);
    sincosf(tf * dv1, &s1, &c1);
    sincosf(dv0, &r0s, &r0c);
    sincosf(dv1, &r1s, &r1c);
    float* row = tab + (size_t)(tb * 16) * D_ + d4 * 4;
#pragma unroll
    for (int u = 0; u < 16; ++u) {
      f32x4 v; v[0] = s0; v[1] = c0; v[2] = s1; v[3] = c1;
      *(f32x4*)row = v;
      row += D_;
      float ns0 = fmaf(s0, r0c, c0 * r0s), nc0 = fmaf(c0, r0c, -s0 * r0s);
      s0 = ns0; c0 = nc0;
      float ns1 = fmaf(s1, r1c, c1 * r1s), nc1 = fmaf(c1, r1c, -s1 * r1s);
      s1 = ns1; c1 = nc1;
    }
  } else if (j < 96) {                  // ---- xbf + cnt rows ----
    int r = (j - 32) * 512 + tid;       // r = b*T + t, 0..32767
    const float4* xr = (const float4*)(x + (size_t)r * 8);
    float4 lo = xr[0], hi = xr[1];
    bf16x8 v;
    v[0] = f2bf(lo.x); v[1] = f2bf(lo.y); v[2] = f2bf(lo.z); v[3] = f2bf(lo.w);
    v[4] = f2bf(hi.x); v[5] = f2bf(hi.y); v[6] = f2bf(hi.z); v[7] = f2bf(hi.w);
    *(bf16x8*)(xbf + (size_t)r * 8) = v;
    int4 mk = *(const int4*)(xmark + (size_t)r * 4);
    bf16x8 cv;
#pragma unroll
    for (int p = 0; p < 8; ++p) {
      int cc = (mk.x == p) + (mk.y == p) + (mk.z == p) + (mk.w == p);
      cv[p] = f2bf((float)cc);
    }
    *(bf16x8*)(cnt + (size_t)r * 8) = cv;
  } else {                              // ---- amat ----
    int d = tid;                        // 0..511
    short row[32];
#pragma unroll
    for (int kk = 0; kk < 24; ++kk) {
      int g = kk >> 3, n = kk & 7;      // A[d][g*8+n] = W[d][n][k=g]
      row[kk] = f2bf(convw[d * 24 + n * 3 + g]);
    }
    float divv = expf((float)(d >> 1) * NEG_LDIV);
    float s1, c1;
    sincosf(divv, &s1, &c1);
    int odd = d & 1;
    row[24] = f2bf(odd ? 1.f : 0.f);
    float ps = s1, pc = c1;
    row[25] = f2bf(odd ? pc : ps);
#pragma unroll
    for (int p = 2; p < 7; ++p) {
      float ns = fmaf(ps, c1, pc * s1);
      float nc = fmaf(pc, c1, -ps * s1);
      ps = ns; pc = nc;
      row[24 + p] = f2bf(odd ? pc : ps);
    }
    row[31] = 0;                        // marks < 7
#pragma unroll
    for (int q = 0; q < 4; ++q)
      *(bf16x8*)(amat + d * 32 + q * 8) = *(bf16x8*)&row[q * 8];
  }
}

// ---- main (R15 body — HBM-roofline per R16): MFMA (conv slots 0..23 +
// temporal 24..31) -> LDS repack -> 4 x 8 KB sequential store rounds.
// Block = 16-row t-tile x 512 d x 2 batches; pmax is 1 value per bn.
__global__ __launch_bounds__(512, 6) void main_kernel(
    const short* __restrict__ amat, const short* __restrict__ xbf,
    const short* __restrict__ cnt, const float* __restrict__ tab,
    const float* __restrict__ pmax, const float* __restrict__ nyqS,
    float* __restrict__ out) {
  __shared__ __align__(16) float lds[16 * LPAD];
  int tid = threadIdx.x;
  int lane = tid & 63;
  int w = tid >> 6;
  int c = lane & 15;
  int g = lane >> 4;
  int blk = blockIdx.x;
  int ttile = blk & 127;
  int bg = blk >> 7;
  int t0 = ttile * 16;

  float w1v[2], w0v[2];
#pragma unroll
  for (int j = 0; j < 2; ++j) {
    int b = bg * 2 + j;
    int m = 0;
#pragma unroll
    for (int nn = 0; nn < 8; ++nn) {
      int bn = b * 8 + nn;
      float mx = pmax[bn];
      float S = nyqS[bn];
      if (S * S > mx) ++m;
    }
    w1v[j] = (float)(8 - m) * 0.125f;
    w0v[j] = (float)m * 0.125f;
  }

  bf16x8 afrag[DTW];
  f32x4 fet[DTW];
#pragma unroll
  for (int q = 0; q < DTW; ++q) {
    int d0 = (w * DTW + q) * 16;
    afrag[q] = *(const bf16x8*)(amat + (size_t)(d0 + c) * 32 + g * 8);
    fet[q] = *(const f32x4*)(tab + (size_t)(t0 + c) * D_ + d0 + g * 4);
  }

  const f32x4 zac = {0.f, 0.f, 0.f, 0.f};
#pragma unroll
  for (int j = 0; j < 2; ++j) {
    int b = bg * 2 + j;
    bf16x8 bfrag;
    if (g < 3) {
      int row = (t0 + c + g - 1) & (T_ - 1);    // circular pad
      bfrag = *(const bf16x8*)(xbf + ((size_t)b * T_ + row) * 8);
    } else {
      bfrag = *(const bf16x8*)(cnt + ((size_t)b * T_ + t0 + c) * 8);
    }
    float w1 = w1v[j], w0 = w0v[j];
#pragma unroll
    for (int q = 0; q < DTW; ++q) {
      f32x4 acc = __builtin_amdgcn_mfma_f32_16x16x32_bf16(
          afrag[q], bfrag, zac, 0, 0, 0);
      f32x4 ov;
      ov[0] = fmaf(w1, fet[q][0], acc[0]);
      ov[1] = fmaf(w1, fet[q][1], acc[1]) + w0;
      ov[2] = fmaf(w1, fet[q][2], acc[2]);
      ov[3] = fmaf(w1, fet[q][3], acc[3]) + w0;
      int d0 = (w * DTW + q) * 16;
      *(f32x4*)(lds + c * LPAD + d0 + g * 4) = ov;
    }
    __syncthreads();
    float* obase = out + ((size_t)b * T_ + t0) * D_;
#pragma unroll
    for (int r = 0; r < 4; ++r) {
      int e = r * 2048 + tid * 4;
      int trow = e >> 9, col = e & 511;
      f32x4 v = *(const f32x4*)(lds + trow * LPAD + col);
      *(f32x4*)(obase + e) = v;
    }
    if (j == 0) __syncthreads();
  }
}

extern "C" void kernel_launch(void* const* d_in, const int* in_sizes, int n_in,
                              void* d_out, int out_size, void* d_ws, size_t ws_size,
                              hipStream_t stream) {
  const float* x = (const float*)d_in[0];
  const int* xmark = (const int*)d_in[1];
  const float* convw = (const float*)d_in[2];
  float* out = (float*)d_out;

  char* ws = (char*)d_ws;
  float* pmax = (float*)ws;                            // 128 f
  float* nyqS = (float*)(ws + 2048);                   // 128 f
  float* tab = (float*)(ws + 8192);                    // 4 MB FET
  short* amat = (short*)(ws + 8192 + 4194304);         // 32 KB
  short* xbf = (short*)(ws + 8192 + 4194304 + 32768);  // 512 KB
  short* cnt = (short*)(ws + 8192 + 4194304 + 32768 + 524288);  // 512 KB

  prep_kernel<<<225, 512, 0, stream>>>(x, xmark, convw, pmax, nyqS, tab,
                                       amat, xbf, cnt);
  main_kernel<<<(T_ / 16) * (B_ / 2), 512, 0, stream>>>(amat, xbf, cnt, tab,
                                                        pmax, nyqS, out);
}

// Round 22
// 26.002 us; speedup vs baseline: 2.8999x; 1.0428x over previous
//
#include <hip/hip_runtime.h>
#include <math.h>

#define B_ 16
#define T_ 2048
#define N_ 8
#define D_ 512
#define LP2 264         // LDS row pitch for 256-col tile (words)

// -pi/1024 ( = -2*pi/2048 )
#define NEG_W0 (-3.0679615757712823e-3f)
// -2*ln(10000)/512
#define NEG_LDIV (-0.035977892078031555f)

typedef __attribute__((ext_vector_type(8))) short bf16x8;
typedef __attribute__((ext_vector_type(4))) float f32x4;

// fp32 -> bf16 (round-to-nearest-even)
static __device__ __forceinline__ short f2bf(float f) {
  unsigned int u = __float_as_uint(f);
  unsigned int r = u + 0x7FFFu + ((u >> 16) & 1u);
  return (short)(r >> 16);
}

// ws layout (byte offsets): [0,512) pmax[128] (ONE value per bn);
// [2048,2560) nyqS[128]; [8K,8K+4M) FET tab f32[2048][512];
// +4M: amat bf16[512][32] (32 KB); xbf bf16[16][2048][8] (512 KB);
// cnt bf16[16][2048][8] (512 KB). All rewritten unconditionally every call.

// ---- prep: 321 blocks x 512 thr, one scheduling round.
//  blk 0..127 : per-(b,n) spectrum via complex 1024-pt radix-2 DIT FFT of
//    z_t = x_{2t} + i x_{2t+1} (R20-validated; 10 LDS stages, table
//    twiddles, index padding), untangle to X_k, Nyquist free.
//    Single writer: pmax[bn], nyqS[bn].
//  blk 128..255: FET tabgen — direct sincosf, 4 float4/thread
//    (R21 BUG: 2/thread covered only t<1024; rows t>=1024 were garbage).
//  blk 256..319: xbf + cnt rows
//  blk 320     : amat
__global__ __launch_bounds__(512) void prep_kernel(
    const float* __restrict__ x, const int* __restrict__ xmark,
    const float* __restrict__ convw, float* __restrict__ pmax,
    float* __restrict__ nyqS, float* __restrict__ tab,
    short* __restrict__ amat, short* __restrict__ xbf,
    short* __restrict__ cnt) {
  __shared__ __align__(16) float2 zs[1088];   // 1024 + pad(i>>4)
  __shared__ __align__(16) float2 tws[544];   // 512 + pad
  __shared__ float red[8];
  int tid = threadIdx.x;
  int blk = blockIdx.x;

  if (blk < 128) {
    // ---- fft role (R20-validated) ----
    int bn = blk;
    int b = bn >> 3, n = bn & 7;
    const float* xb = x + (size_t)b * (T_ * N_) + n;

    {  // twiddle table: tws[k] = e^{-2pi i k/1024}
      float ss, cc;
      sincosf((float)tid * (2.0f * NEG_W0), &ss, &cc);
      tws[tid + (tid >> 4)] = make_float2(cc, ss);
    }
#pragma unroll
    for (int u = 0; u < 2; ++u) {   // load, bit-reversed placement
      int tau = tid + u * 512;
      float re = xb[(2 * tau) * 8];
      float im = xb[(2 * tau + 1) * 8];
      int p = __brev(tau) >> 22;    // 10-bit reversal
      zs[p + (p >> 4)] = make_float2(re, im);
    }
    __syncthreads();

#pragma unroll
    for (int s = 1; s <= 10; ++s) { // radix-2 DIT stages
      int half = 1 << (s - 1);
      int idx = tid & (half - 1);
      int grp = tid >> (s - 1);
      int p0 = grp * (half << 1) + idx;
      int p1 = p0 + half;
      int ti = idx << (10 - s);
      float2 tw = tws[ti + (ti >> 4)];
      float2 a = zs[p0 + (p0 >> 4)];
      float2 bv = zs[p1 + (p1 >> 4)];
      float tr = bv.x * tw.x - bv.y * tw.y;
      float tq = fmaf(bv.x, tw.y, bv.y * tw.x);
      zs[p1 + (p1 >> 4)] = make_float2(a.x - tr, a.y - tq);
      zs[p0 + (p0 >> 4)] = make_float2(a.x + tr, a.y + tq);
      __syncthreads();
    }

    // untangle: thread j covers bins k=j and k=1024-j
    int j = tid;
    int jm = (1024 - j) & 1023;
    float2 A = zs[j + (j >> 4)];
    float2 Bv = zs[jm + (jm >> 4)];
    float u = A.x - Bv.x, v = A.y + Bv.y;
    float Ere = 0.5f * (A.x + Bv.x), Eim = 0.5f * (A.y - Bv.y);
    float Ore = 0.5f * v, Oim = -0.5f * u;
    float cw, sw;
    sincosf((float)j * NEG_W0, &sw, &cw);
    float Gr = Ere + cw * Ore - sw * Oim;       // X_j
    float Gi = Eim + cw * Oim + sw * Ore;
    float P = fmaf(Gr, Gr, Gi * Gi);
    float Gpr = Ere - cw * Ore + sw * Oim;      // X_{1024-j}
    float Gpi = -Eim + cw * Oim + sw * Ore;
    float P2;
    if (j == 0) {
      nyqS[bn] = Gpr;                           // X_1024 (excluded from max)
      float2 Am = zs[512 + (512 >> 4)];         // k=512: X = conj(Z_512)
      P2 = fmaf(Am.x, Am.x, Am.y * Am.y);
    } else {
      P2 = fmaf(Gpr, Gpr, Gpi * Gpi);
    }
    P = fmaxf(P, P2);
#pragma unroll
    for (int off = 32; off > 0; off >>= 1) P = fmaxf(P, __shfl_down(P, off));
    if ((tid & 63) == 0) red[tid >> 6] = P;
    __syncthreads();
    if (tid == 0) {
      float mx = red[0];
#pragma unroll
      for (int k = 1; k < 8; ++k) mx = fmaxf(mx, red[k]);
      pmax[bn] = mx;                            // single unconditional writer
    }
    return;
  }

  int j = blk - 128;
  if (j < 128) {                        // ---- FET tabgen (full coverage) ----
    int base = j * 2048 + tid * 4;      // 128 blk x 512 thr x 4 = 262144 f4
#pragma unroll
    for (int u = 0; u < 4; ++u) {
      int idx = base + u;
      int t = idx >> 7;
      int d4 = idx & 127;
      float ft = (float)t;
      float dv0 = expf((float)(d4 * 2) * NEG_LDIV);
      float dv1 = expf((float)(d4 * 2 + 1) * NEG_LDIV);
      f32x4 v;
      float s0, c0, s1, c1;
      sincosf(ft * dv0, &s0, &c0);
      sincosf(ft * dv1, &s1, &c1);
      v[0] = s0; v[1] = c0; v[2] = s1; v[3] = c1;
      *(f32x4*)(tab + (size_t)idx * 4) = v;
    }
  } else if (j < 192) {                 // ---- xbf + cnt rows ----
    int r = (j - 128) * 512 + tid;      // r = b*T + t, 0..32767
    const float4* xr = (const float4*)(x + (size_t)r * 8);
    float4 lo = xr[0], hi = xr[1];
    bf16x8 v;
    v[0] = f2bf(lo.x); v[1] = f2bf(lo.y); v[2] = f2bf(lo.z); v[3] = f2bf(lo.w);
    v[4] = f2bf(hi.x); v[5] = f2bf(hi.y); v[6] = f2bf(hi.z); v[7] = f2bf(hi.w);
    *(bf16x8*)(xbf + (size_t)r * 8) = v;
    int4 mk = *(const int4*)(xmark + (size_t)r * 4);
    bf16x8 cv;
#pragma unroll
    for (int p = 0; p < 8; ++p) {
      int cc = (mk.x == p) + (mk.y == p) + (mk.z == p) + (mk.w == p);
      cv[p] = f2bf((float)cc);
    }
    *(bf16x8*)(cnt + (size_t)r * 8) = cv;
  } else {                              // ---- amat ----
    int d = tid;                        // 0..511
    short row[32];
#pragma unroll
    for (int kk = 0; kk < 24; ++kk) {
      int g = kk >> 3, n = kk & 7;      // A[d][g*8+n] = W[d][n][k=g]
      row[kk] = f2bf(convw[d * 24 + n * 3 + g]);
    }
    float divv = expf((float)(d >> 1) * NEG_LDIV);
    float s1, c1;
    sincosf(divv, &s1, &c1);
    int odd = d & 1;
    row[24] = f2bf(odd ? 1.f : 0.f);
    float ps = s1, pc = c1;
    row[25] = f2bf(odd ? pc : ps);
#pragma unroll
    for (int p = 2; p < 7; ++p) {
      float ns = fmaf(ps, c1, pc * s1);
      float nc = fmaf(pc, c1, -ps * s1);
      ps = ns; pc = nc;
      row[24 + p] = f2bf(odd ? pc : ps);
    }
    row[31] = 0;                        // marks < 7
#pragma unroll
    for (int q = 0; q < 4; ++q)
      *(bf16x8*)(amat + d * 32 + q * 8) = *(bf16x8*)&row[q * 8];
  }
}

// ---- main: 2048 x 256-thr blocks = EXACTLY one scheduling round at
// 8 blocks/CU (32 waves/CU) — removes R15's 1.33-round ragged tail.
// Block = (ttile, batch-pair, d-half): 16 t-rows x 256 d x 2 batches.
// Same MFMA structure (conv slots 0..23 + temporal 24..31), LDS repack,
// 4 x 4 KB sequential store rounds (1 KB contiguous per wave-inst).
// Register diet: afrag re-loaded per batch (amat is 32 KB L2-hot).
__global__ __launch_bounds__(256, 8) void main_kernel(
    const short* __restrict__ amat, const short* __restrict__ xbf,
    const short* __restrict__ cnt, const float* __restrict__ tab,
    const float* __restrict__ pmax, const float* __restrict__ nyqS,
    float* __restrict__ out) {
  __shared__ __align__(16) float lds[16 * LP2];
  int tid = threadIdx.x;
  int lane = tid & 63;
  int w = tid >> 6;            // wave 0..3
  int c = lane & 15;           // t-col / A d-row
  int g = lane >> 4;           // k-slot group / C d-subgroup
  int blk = blockIdx.x;
  int ttile = blk & 127;
  int rest = blk >> 7;         // 0..15
  int bg = rest & 7;           // batches bg*2, bg*2+1
  int dhalf = rest >> 3;       // d in [dhalf*256, dhalf*256+256)
  int t0 = ttile * 16;
  int dbase = dhalf * 256;

  float w1v[2], w0v[2];
#pragma unroll
  for (int j = 0; j < 2; ++j) {
    int b = bg * 2 + j;
    int m = 0;
#pragma unroll
    for (int nn = 0; nn < 8; ++nn) {
      int bn = b * 8 + nn;
      float mx = pmax[bn];
      float S = nyqS[bn];
      if (S * S > mx) ++m;
    }
    w1v[j] = (float)(8 - m) * 0.125f;
    w0v[j] = (float)m * 0.125f;
  }

  // fet persistent in regs (reused by both batches); afrag loaded per batch
  f32x4 fet[4];
#pragma unroll
  for (int q = 0; q < 4; ++q) {
    int dq = dbase + (w * 4 + q) * 16;
    fet[q] = *(const f32x4*)(tab + (size_t)(t0 + c) * D_ + dq + g * 4);
  }

  const f32x4 zac = {0.f, 0.f, 0.f, 0.f};
#pragma unroll
  for (int j = 0; j < 2; ++j) {
    int b = bg * 2 + j;
    bf16x8 bfrag;
    if (g < 3) {
      int row = (t0 + c + g - 1) & (T_ - 1);    // circular pad
      bfrag = *(const bf16x8*)(xbf + ((size_t)b * T_ + row) * 8);
    } else {
      bfrag = *(const bf16x8*)(cnt + ((size_t)b * T_ + t0 + c) * 8);
    }
    float w1 = w1v[j], w0 = w0v[j];
#pragma unroll
    for (int q = 0; q < 4; ++q) {
      int dq = dbase + (w * 4 + q) * 16;
      bf16x8 afrag = *(const bf16x8*)(amat + (size_t)(dq + c) * 32 + g * 8);
      f32x4 acc = __builtin_amdgcn_mfma_f32_16x16x32_bf16(
          afrag, bfrag, zac, 0, 0, 0);
      f32x4 ov;
      ov[0] = fmaf(w1, fet[q][0], acc[0]);
      ov[1] = fmaf(w1, fet[q][1], acc[1]) + w0;
      ov[2] = fmaf(w1, fet[q][2], acc[2]);
      ov[3] = fmaf(w1, fet[q][3], acc[3]) + w0;
      *(f32x4*)(lds + c * LP2 + (w * 4 + q) * 16 + g * 4) = ov;
    }
    __syncthreads();
    // stream the 16x256 tile out: 4 rounds x 4 KB, 1 KB/wave-inst contiguous
    float* obase = out + ((size_t)b * T_ + t0) * D_ + dbase;
#pragma unroll
    for (int r = 0; r < 4; ++r) {
      int e = r * 1024 + tid * 4;               // element offset in tile
      int trow = e >> 8, col = e & 255;
      f32x4 v = *(const f32x4*)(lds + trow * LP2 + col);
      *(f32x4*)(obase + trow * D_ + col) = v;
    }
    if (j == 0) __syncthreads();                // last iter: no LDS reuse
  }
}

extern "C" void kernel_launch(void* const* d_in, const int* in_sizes, int n_in,
                              void* d_out, int out_size, void* d_ws, size_t ws_size,
                              hipStream_t stream) {
  const float* x = (const float*)d_in[0];
  const int* xmark = (const int*)d_in[1];
  const float* convw = (const float*)d_in[2];
  float* out = (float*)d_out;

  char* ws = (char*)d_ws;
  float* pmax = (float*)ws;                            // 128 f
  float* nyqS = (float*)(ws + 2048);                   // 128 f
  float* tab = (float*)(ws + 8192);                    // 4 MB FET
  short* amat = (short*)(ws + 8192 + 4194304);         // 32 KB
  short* xbf = (short*)(ws + 8192 + 4194304 + 32768);  // 512 KB
  short* cnt = (short*)(ws + 8192 + 4194304 + 32768 + 524288);  // 512 KB

  prep_kernel<<<321, 512, 0, stream>>>(x, xmark, convw, pmax, nyqS, tab,
                                       amat, xbf, cnt);
  main_kernel<<<2048, 256, 0, stream>>>(amat, xbf, cnt, tab, pmax, nyqS, out);
}